// Round 10
// baseline (141.200 us; speedup 1.0000x reference)
//
#include <hip/hip_runtime.h>
#include <cmath>

// SelfMutualAttention: b=2, c=256, n=4096, H=8, d=32.
// R8: revert to R6 (last passing) + exactly ONE delta: attn is now a
// 512-thread / 8-wave block; each wave = 2 q-sets x KV-eighth (16 iters),
// VALU lsum (no sum-MFMA AGPRs), single-pass 73.7KB LDS combine, emit by
// waves 0-3 using R6's exact fragment formulas. No atomics, no overlay
// changes, no ws growth. launch_bounds(512,4) -> 2 blocks/CU = 16 waves/CU.

typedef unsigned int u32;
typedef unsigned short u16;
typedef __attribute__((ext_vector_type(4))) float f32x4;
typedef __attribute__((ext_vector_type(16))) float f32x16;
typedef __attribute__((ext_vector_type(8))) short short8;
typedef __attribute__((ext_vector_type(4))) u32 u32x4;

__device__ __forceinline__ u32 cvtpk_bf16(float a, float b) {
  u32 r; asm("v_cvt_pk_bf16_f32 %0, %1, %2" : "=v"(r) : "v"(a), "v"(b)); return r;
}
__device__ __forceinline__ u16 f2bf(float x) { return (u16)cvtpk_bf16(x, x); }

__device__ __forceinline__ f32x16 mfma16(short8 a, short8 b, f32x16 c) {
  return __builtin_amdgcn_mfma_f32_32x32x16_bf16(a, b, c, 0, 0, 0);
}

// hi = truncated bf16, lo = residual (RNE) -- packed pairs
__device__ __forceinline__ void split2(float a, float b, u32 &hw, u32 &lw) {
  u32 ua = __builtin_bit_cast(u32, a), ub = __builtin_bit_cast(u32, b);
  hw = (ua >> 16) | (ub & 0xffff0000u);
  float ra = a - __builtin_bit_cast(float, ua & 0xffff0000u);
  float rb = b - __builtin_bit_cast(float, ub & 0xffff0000u);
  lw = cvtpk_bf16(ra, rb);
}
__device__ __forceinline__ void split8(f32x4 a, f32x4 b, short8 &hf, short8 &lf) {
  u32 h0,l0,h1,l1,h2,l2,h3,l3;
  split2(a[0],a[1],h0,l0); split2(a[2],a[3],h1,l1);
  split2(b[0],b[1],h2,l2); split2(b[2],b[3],h3,l3);
  u32x4 hv = {h0,h1,h2,h3}, lv = {l0,l1,l2,l3};
  hf = __builtin_bit_cast(short8, hv);
  lf = __builtin_bit_cast(short8, lv);
}

// D row for (reg r, lane-hi): (r&3) + 8*((r>>2)&1) + 4*hi + 16*(r>>3)
__device__ __forceinline__ int rowmap(int r, int hi) {
  return (r & 3) + 8 * ((r >> 2) & 1) + 4 * hi + 16 * (r >> 3);
}
// kv -> V-tile storage slot: swap bits 2 and 3 (matches P k-slot order)
__device__ __forceinline__ int tau(int kv) {
  return (kv & 19) | ((kv & 4) << 1) | ((kv & 8) >> 1);
}

#define QMUL (0.17677669529663689f * 1.4426950408889634f)  // d^-0.5 * log2e
#define WPLANE 65536   // u16 stride between hi/lo planes of one W matrix
#define WMAT  131072   // u16 stride between packed W matrices

// ---------------- k0: prep (X transpose-to-frags + W pack) -----------------
__global__ __launch_bounds__(256) void prep_kernel(
    const float* __restrict__ X,
    const float* __restrict__ Wq, const float* __restrict__ Wk,
    const float* __restrict__ Wv, const float* __restrict__ Wo,
    u16* __restrict__ Xa, u16* __restrict__ Wpk)
{
  const int bx = blockIdx.x, tid = threadIdx.x;
  if (bx < 256) {
    __shared__ float lt[32 * 257];
    const int b = bx >> 7, ntile = bx & 127, n0 = ntile * 32;
    const int nn = tid & 31, cg = tid >> 5;
    #pragma unroll 4
    for (int i = 0; i < 32; i++) {
      int c = i * 8 + cg;
      lt[nn * 257 + c] = X[((size_t)b * 256 + c) * 4096 + n0 + nn];
    }
    __syncthreads();
    const int lane = tid & 63, w = tid >> 6;
    const int l31 = lane & 31, fh = lane >> 5;
    #pragma unroll
    for (int kk = 0; kk < 4; kk++) {
      int kt = w * 4 + kk;
      const float* p = &lt[l31 * 257 + kt * 16 + fh * 8];
      u32x4 pk = { cvtpk_bf16(p[0],p[1]), cvtpk_bf16(p[2],p[3]),
                   cvtpk_bf16(p[4],p[5]), cvtpk_bf16(p[6],p[7]) };
      *(u32x4*)(&Xa[(((size_t)b * 128 + ntile) * 16 + kt) * 512 + lane * 8]) = pk;
    }
  } else {
    const int j = (bx - 256) * 256 + tid;
    const int lane = j & 63, ct = (j >> 6) & 7, kt = (j >> 9) & 15, mat = j >> 13;
    const float* W = mat == 0 ? Wq : (mat == 1 ? Wk : (mat == 2 ? Wv : Wo));
    const int c = ct * 32 + (lane & 31);
    const int k0 = kt * 16 + (lane >> 5) * 8;
    f32x4 a = *(const f32x4*)(W + (size_t)c * 256 + k0);
    f32x4 b = *(const f32x4*)(W + (size_t)c * 256 + k0 + 4);
    if (mat == 0) {
      #pragma unroll
      for (int i = 0; i < 4; i++) { a[i] *= QMUL; b[i] *= QMUL; }
    }
    short8 wh, wl; split8(a, b, wh, wl);
    size_t base = ((size_t)mat * 2) * WPLANE + ((size_t)kt * 8 + ct) * 512 + lane * 8;
    *(short8*)(&Wpk[base]) = wh;
    *(short8*)(&Wpk[base + WPLANE]) = wl;
  }
}

// ---------------- k1: QKV projection (fragment streaming GEMM) -------------
// grid (128 ntile, 1, 6 = b*3+mode), 256 thr. Wave: 1 n-tile x 2 heads.
__global__ __launch_bounds__(256) void qkv_kernel(
    const u16* __restrict__ Xa, const u16* __restrict__ Wpk,
    const float* __restrict__ bq, const float* __restrict__ bk,
    const float* __restrict__ bv,
    u16* __restrict__ Qf, u16* __restrict__ Kf, u16* __restrict__ V3)
{
  const int z = blockIdx.z, mode = z % 3, b = z / 3;
  const int tid = threadIdx.x, lane = tid & 63, wv = tid >> 6;
  const int ntile = blockIdx.x;
  const int l31 = lane & 31, fh = lane >> 5;

  const u16* Amat = Xa + ((size_t)b * 128 + ntile) * 8192;
  const u16* Bmat = Wpk + (size_t)mode * WMAT;

  f32x16 acc[2] = {{}, {}};
  for (int kt = 0; kt < 16; kt++) {
    short8 xa = *(const short8*)(Amat + kt * 512 + lane * 8);
    #pragma unroll
    for (int i = 0; i < 2; i++) {
      int ct = wv * 2 + i;
      const u16* wp = Bmat + ((size_t)kt * 8 + ct) * 512 + lane * 8;
      short8 wh = *(const short8*)(wp);
      short8 wl = *(const short8*)(wp + WPLANE);
      acc[i] = mfma16(wh, xa, acc[i]);   // A=W (regs=c), B=Xa (lanes=n)
      acc[i] = mfma16(wl, xa, acc[i]);
    }
  }

  const float* bias = mode == 0 ? bq : (mode == 1 ? bk : bv);
  const float bscale = mode == 0 ? QMUL : 1.0f;

  if (mode == 2) {
    // V3 [bh][kvt=ntile][dv 32][slot 32], slot = tau(kv): PV A-frag aligned
    const int sl = tau(l31);
    #pragma unroll
    for (int i = 0; i < 2; i++) {
      int head = wv * 2 + i;
      size_t tb = ((size_t)(b * 8 + head) * 128 + ntile) * 1024;
      #pragma unroll
      for (int r = 0; r < 16; r++) {
        int dv = rowmap(r, fh);
        V3[tb + (size_t)dv * 32 + sl] = f2bf(acc[i][r] + bias[head * 32 + dv]);
      }
    }
  } else {
    u16* Out = mode == 0 ? Qf : Kf;
    #pragma unroll
    for (int i = 0; i < 2; i++) {
      int head = wv * 2 + i;
      size_t nb = ((size_t)(b * 8 + head) * 128 + ntile) * 1024;
      #pragma unroll
      for (int kt2 = 0; kt2 < 2; kt2++) {
        float v[8];
        #pragma unroll
        for (int e = 0; e < 8; e++) {
          int c = head * 32 + rowmap(kt2 * 8 + e, fh);
          v[e] = acc[i][kt2 * 8 + e] + bscale * bias[c];
        }
        u32x4 pk = { cvtpk_bf16(v[0],v[1]), cvtpk_bf16(v[2],v[3]),
                     cvtpk_bf16(v[4],v[5]), cvtpk_bf16(v[6],v[7]) };
        *(u32x4*)(&Out[nb + (size_t)kt2 * 512 + lane * 8]) = pk;
      }
    }
  }
}

// ---------------- k2: fused flash attention --------------------------------
// grid 1024 x 512 thr (8 waves). Block = 64 q-rows of one (b,h); each wave
// owns a KV-eighth (16 tiles) and both q-sets. Single-pass LDS combine of
// the 8 partials; waves 0-3 emit O as hi/lo bf16 fragment planes.
__global__ __launch_bounds__(512, 4) void attn_kernel(
    const u16* __restrict__ Qf, const u16* __restrict__ Kf,
    const u16* __restrict__ V3, u16* __restrict__ OaH, u16* __restrict__ OaL)
{
  const int fid = blockIdx.x;
  const int xcd = fid & 7, j = fid >> 3;       // j in [0,128)
  const int bh = xcd + 8 * (j >> 6);           // bh pinned per XCD
  const int qgrp = j & 63;
  const int b = bh >> 3, h = bh & 7;

  const int tid = threadIdx.x, wv = tid >> 6, lane = tid & 63;
  const int l31 = lane & 31, fh = lane >> 5;

  const u16* qfb = Qf + (size_t)bh * 131072 + (size_t)(qgrp * 2) * 1024 + lane * 8;
  short8 qa0 = *(const short8*)(qfb);
  short8 qa1 = *(const short8*)(qfb + 512);
  short8 qb0 = *(const short8*)(qfb + 1024);
  short8 qb1 = *(const short8*)(qfb + 1536);

  const u16* kfb = Kf + (size_t)bh * 131072;
  const u16* vfb = V3 + (size_t)bh * 131072;

  f32x16 accA = {}, accB = {};
  float lsA0 = 0.f, lsA1 = 0.f, lsB0 = 0.f, lsB1 = 0.f;

  for (int it = 0; it < 16; it++) {
    const int kvt = wv * 16 + it;              // this wave's KV-eighth
    const u16* kp = kfb + (size_t)kvt * 1024 + lane * 8;
    const u16* vp = vfb + (size_t)kvt * 1024 + l31 * 32 + fh * 8;
    short8 kc0 = *(const short8*)(kp);
    short8 kc1 = *(const short8*)(kp + 512);
    short8 vc0 = *(const short8*)(vp);
    short8 vc1 = *(const short8*)(vp + 16);

    { // ---- q-set A ----
      f32x16 s = {};
      s = mfma16(kc0, qa0, s);                 // S^T[kv regs][q lanes]
      s = mfma16(kc1, qa1, s);
      #pragma unroll
      for (int r = 0; r < 16; r++) s[r] = __builtin_amdgcn_exp2f(s[r]);
      lsA0 += ((s[0]+s[1]) + (s[2]+s[3])) + ((s[4]+s[5]) + (s[6]+s[7]));
      lsA1 += ((s[8]+s[9]) + (s[10]+s[11])) + ((s[12]+s[13]) + (s[14]+s[15]));
      u32x4 u0 = { cvtpk_bf16(s[0],s[1]),  cvtpk_bf16(s[2],s[3]),
                   cvtpk_bf16(s[4],s[5]),  cvtpk_bf16(s[6],s[7]) };
      u32x4 u1 = { cvtpk_bf16(s[8],s[9]),  cvtpk_bf16(s[10],s[11]),
                   cvtpk_bf16(s[12],s[13]),cvtpk_bf16(s[14],s[15]) };
      accA = mfma16(vc0, __builtin_bit_cast(short8,u0), accA);
      accA = mfma16(vc1, __builtin_bit_cast(short8,u1), accA);
    }
    { // ---- q-set B ----
      f32x16 s = {};
      s = mfma16(kc0, qb0, s);
      s = mfma16(kc1, qb1, s);
      #pragma unroll
      for (int r = 0; r < 16; r++) s[r] = __builtin_amdgcn_exp2f(s[r]);
      lsB0 += ((s[0]+s[1]) + (s[2]+s[3])) + ((s[4]+s[5]) + (s[6]+s[7]));
      lsB1 += ((s[8]+s[9]) + (s[10]+s[11])) + ((s[12]+s[13]) + (s[14]+s[15]));
      u32x4 u0 = { cvtpk_bf16(s[0],s[1]),  cvtpk_bf16(s[2],s[3]),
                   cvtpk_bf16(s[4],s[5]),  cvtpk_bf16(s[6],s[7]) };
      u32x4 u1 = { cvtpk_bf16(s[8],s[9]),  cvtpk_bf16(s[10],s[11]),
                   cvtpk_bf16(s[12],s[13]),cvtpk_bf16(s[14],s[15]) };
      accB = mfma16(vc0, __builtin_bit_cast(short8,u0), accB);
      accB = mfma16(vc1, __builtin_bit_cast(short8,u1), accB);
    }
  }

  // ---- single-pass combine of 8 KV-eighth partials; emit O fragments ----
  __shared__ float accb[2][8][64][17];   // 69,632 B
  __shared__ float lsb[2][8][64];        //  4,096 B

  { float ls = lsA0 + lsA1; ls += __shfl_xor(ls, 32); lsb[0][wv][lane] = ls; }
  { float ls = lsB0 + lsB1; ls += __shfl_xor(ls, 32); lsb[1][wv][lane] = ls; }
  #pragma unroll
  for (int r = 0; r < 16; r++) { accb[0][wv][lane][r] = accA[r]; accb[1][wv][lane][r] = accB[r]; }
  __syncthreads();

  if (wv < 4) {
    const int set = wv >> 1, ktl = wv & 1;
    float Lt = 0.f;
    #pragma unroll
    for (int w2 = 0; w2 < 8; w2++) Lt += lsb[set][w2][l31];
    const float Linv = 1.0f / Lt;

    float o[8];
    #pragma unroll
    for (int e = 0; e < 8; e++) {
      int hs = (e >> 2) & 1;
      int r = (e & 3) + 4 * fh + 8 * ktl;
      int li = hs * 32 + l31;
      float v = 0.f;
      #pragma unroll
      for (int w2 = 0; w2 < 8; w2++) v += accb[set][w2][li][r];
      o[e] = v * Linv;
    }
    f32x4 o0 = {o[0], o[1], o[2], o[3]}, o1 = {o[4], o[5], o[6], o[7]};
    short8 oh, ol; split8(o0, o1, oh, ol);
    const int qt = qgrp * 2 + set, ktg = h * 2 + ktl;
    size_t addr = (((size_t)b * 128 + qt) * 16 + ktg) * 512 + lane * 8;
    *(short8*)(&OaH[addr]) = oh;
    *(short8*)(&OaL[addr]) = ol;
  }
}

// ---------------- k3: output projection (fragment GEMM) --------------------
__global__ __launch_bounds__(256) void oproj_kernel(
    const u16* __restrict__ OaH, const u16* __restrict__ OaL,
    const u16* __restrict__ Wpk, const float* __restrict__ bo,
    float* __restrict__ Out)
{
  const int b = blockIdx.z, ct = blockIdx.y;
  const int tid = threadIdx.x, lane = tid & 63, wv = tid >> 6;
  const int ntile = blockIdx.x * 4 + wv;
  const int l31 = lane & 31, fh = lane >> 5;

  const u16* Wo = Wpk + (size_t)3 * WMAT;
  const u16* Ob = OaH + ((size_t)b * 128 + ntile) * 8192;
  const u16* Ol = OaL + ((size_t)b * 128 + ntile) * 8192;

  f32x16 acc = {};
  for (int kt = 0; kt < 16; kt++) {
    const u16* wp = Wo + ((size_t)kt * 8 + ct) * 512 + lane * 8;
    short8 wh = *(const short8*)(wp);
    short8 wl = *(const short8*)(wp + WPLANE);
    short8 oh = *(const short8*)(Ob + kt * 512 + lane * 8);
    short8 ol = *(const short8*)(Ol + kt * 512 + lane * 8);
    acc = mfma16(wh, oh, acc);
    acc = mfma16(wh, ol, acc);
    acc = mfma16(wl, oh, acc);
  }
  #pragma unroll
  for (int r = 0; r < 16; r++) {
    int c = ct * 32 + rowmap(r, fh);
    Out[((size_t)b * 256 + c) * 4096 + ntile * 32 + l31] = acc[r] + bo[c];
  }
}

extern "C" void kernel_launch(void* const* d_in, const int* in_sizes, int n_in,
                              void* d_out, int out_size, void* d_ws, size_t ws_size,
                              hipStream_t stream) {
  const float* x1 = (const float*)d_in[0];
  const float* Wq = (const float*)d_in[1];
  const float* bq = (const float*)d_in[2];
  const float* Wk = (const float*)d_in[3];
  const float* bk = (const float*)d_in[4];
  const float* Wv = (const float*)d_in[5];
  const float* bv = (const float*)d_in[6];
  const float* Wo = (const float*)d_in[7];
  const float* bo = (const float*)d_in[8];

  const size_t NEL = (size_t)2 * 4096 * 256;   // 2M elements
  u16* Xa  = (u16*)d_ws;        // reused as OaH after qkv consumes it
  u16* Qf  = Xa + NEL;
  u16* Kf  = Qf + NEL;
  u16* V3  = Kf + NEL;
  u16* OaL = V3 + NEL;
  u16* Wpk = OaL + NEL;         // 524288 u16
  u16* OaH = Xa;
  float* out = (float*)d_out;

  prep_kernel<<<dim3(384), 256, 0, stream>>>(x1, Wq, Wk, Wv, Wo, Xa, Wpk);
  qkv_kernel<<<dim3(128, 1, 6), 256, 0, stream>>>(Xa, Wpk, bq, bk, bv, Qf, Kf, V3);
  attn_kernel<<<dim3(1024), 512, 0, stream>>>(Qf, Kf, V3, OaH, OaL);
  oproj_kernel<<<dim3(32, 8, 2), 256, 0, stream>>>(OaH, OaL, Wpk, bo, out);
}